// Round 21
// baseline (250.928 us; speedup 1.0000x reference)
//
#include <hip/hip_runtime.h>
#include <hip/hip_fp16.h>

typedef __attribute__((ext_vector_type(8))) short short8;
typedef __attribute__((ext_vector_type(8))) _Float16 half8;
typedef __attribute__((ext_vector_type(4))) float f32x4;
typedef __attribute__((ext_vector_type(2))) float f32x2;
typedef __attribute__((ext_vector_type(4))) unsigned int u32x4;

#define NROWS   262144
#define ODIM    64
#define NBLOCKS 512           // 2 blocks/CU (80 KB LDS each) -> 32 waves/CU
#define TPB     1024
#define NFRAG   (24*4*64)     // full fragment array in d_ws (98304 B)
#define INV2PI  0.15915494309189535f

__device__ __forceinline__ float cos2pi(float f){ float r; asm("v_cos_f32 %0, %1" : "=v"(r) : "v"(f)); return r; }
__device__ __forceinline__ float sin2pi(float f){ float r; asm("v_sin_f32 %0, %1" : "=v"(r) : "v"(f)); return r; }

__device__ __forceinline__ short f16_of(float f){
    union { _Float16 h; short s; } u; u.h = (_Float16)f; return u.s; }
__device__ __forceinline__ unsigned h2b(__half2 h){
    union { __half2 h; unsigned u; } x; x.h = h; return x.u; }
__device__ __forceinline__ half8 u4h(u32x4 v){ union{u32x4 u; half8 h;} x; x.u = v; return x.h; }
__device__ __forceinline__ half8 s8h(short8 v){ union{short8 s; half8 h;} x; x.s = v; return x.h; }

// one packed rotation: (C,S) <- (C*rc - S*rs, S*rc + C*rs), 2 features/inst
#define ADV(C, S, RC, RS, RN) do {                       \
    const __half2 _cn = __hfma2(C, RC, __hmul2(S, RN));  \
    const __half2 _sn = __hfma2(S, RC, __hmul2(C, RS));  \
    C = _cn; S = _sn;                                    \
} while (0)

// ---- prep: fp32 coeffs -> f16 fragment-ordered weights in d_ws (once) ----
// [ks][nt][lane] -> short8 ; k = br*384 + i*128 + g ; W[o,k] = coeffs[br,o,i,g]
extern "C" __global__ void prep_weights(const float* __restrict__ coeffs,
                                        short8* __restrict__ wfrag)
{
    const int fl = blockIdx.x * 256 + threadIdx.x;
    if (fl >= NFRAG) return;
    const int ks = fl >> 8;
    const int nt = (fl >> 6) & 3;
    const int ln = fl & 63;
    const int o  = nt*16 + (ln & 15);   // B-frag: col = lane & 15
    const int kg = ln >> 4;             // k sub-band = 4*(lane>>4)
    union { short8 v; short s[8]; } fr;
    #pragma unroll
    for (int h = 0; h < 2; ++h) {
        const int kb  = ks*32 + h*16;
        const int br  = (kb >= 384) ? 1 : 0;
        const int rem = kb - br*384;
        const int ii  = rem >> 7;
        const int g0  = (rem & 127) + kg*4;
        const float* wp = coeffs + (((br*ODIM + o)*3 + ii) << 7) + g0;
        #pragma unroll
        for (int j = 0; j < 4; ++j) fr.s[h*4 + j] = f16_of(wp[j]);
    }
    wfrag[fl] = fr.v;
}

// out[b,o] = sum_k F[b,k] W[o,k]; cos k-step kk (0..11) pairs with sin kk+12.
// R21: 80 KB LDS (ks 0..9 and 12..21 -> slots 0..19) so 2 blocks/CU co-reside;
// kk 10,11 read b-frags from the L2-resident d_ws array. One 32-row pass/wave.
extern "C" __global__ void __launch_bounds__(TPB, 8)
fourier_main(const float* __restrict__ x,
             const short8* __restrict__ wfrag,
             const float* __restrict__ bias,
             float* __restrict__ out)
{
    __shared__ short8 Wlds[20 * 4 * 64];   // 81920 B

    const int tid = threadIdx.x;

    // coalesced d_ws -> LDS copy of the 20 resident ks-tiles
    #pragma unroll
    for (int c = 0; c < 5; ++c) {
        const int i    = c*TPB + tid;       // 0..5119
        const int slot = i >> 8;            // 0..19
        const int ks   = (slot < 10) ? slot : slot + 2;
        Wlds[i] = wfrag[ks*256 + (i & 255)];
    }
    __syncthreads();

    const int lane = tid & 63;
    const int wid  = tid >> 6;
    const int mrow = lane & 15;     // A-frag row within 16-row tile
    const int kgrp = lane >> 4;     // k sub-band / D-row group
    const float hs = (float)(4*kgrp + 1);   // lane's anchor harmonic per i-block

    float bcol[4];
    #pragma unroll
    for (int nt = 0; nt < 4; ++nt) bcol[nt] = bias[nt*16 + mrow];

    const int task = blockIdx.x * 16 + wid;   // 512*16 = 8192 = NROWS/32, exact
    const int base = task * 32;
    const int rowA = base + mrow;
    const int rowB = base + 16 + mrow;

    f32x2 xr[3];
    #pragma unroll
    for (int i = 0; i < 3; ++i)
        xr[i] = (f32x2){ x[rowA*3 + i] * INV2PI, x[rowB*3 + i] * INV2PI };

    f32x4 acc[2][4];
    #pragma unroll
    for (int rr = 0; rr < 2; ++rr)
        #pragma unroll
        for (int nt = 0; nt < 4; ++nt)
            acc[rr][nt] = (f32x4){0.f, 0.f, 0.f, 0.f};

    // chain state + rotation constants (per row)
    __half2 C0, S0, C1, S1;
    __half2 c2h0, s2h0, n2h0, c14h0, s14h0, n14h0;
    __half2 c2h1, s2h1, n2h1, c14h1, s14h1, n14h1;

    #pragma unroll 1
    for (int kk = 0; kk < 12; ++kk) {          // cos k-step; sin is kk+12
        // early-issue this step's 8 b-frags (latency hides under feature gen)
        short8 bfr[8];                          // [branch*4 + nt], static idx
        if (kk < 10) {                          // uniform branch
            #pragma unroll
            for (int nt = 0; nt < 4; ++nt) {
                bfr[nt]     = Wlds[(kk*4 + nt)*64 + lane];          // slot kk
                bfr[4 + nt] = Wlds[((kk + 10)*4 + nt)*64 + lane];   // slot kk+10 = ks kk+12
            }
        } else {                                // kk 10,11: L2-resident d_ws
            #pragma unroll
            for (int nt = 0; nt < 4; ++nt) {
                bfr[nt]     = wfrag[(kk*4 + nt)*64 + lane];         // ks kk
                bfr[4 + nt] = wfrag[((kk + 12)*4 + nt)*64 + lane];  // ks kk+12
            }
        }

        if ((kk & 3) == 0) {                    // re-anchor per i-block (uniform)
            const int i = kk >> 2;
            const f32x2 a = xr[i];
            {   // row 0
                const float av = a.x;
                float u0 = hs*av;        u0 -= floorf(u0);
                float u1 = (hs+1.f)*av;  u1 -= floorf(u1);
                C0 = __floats2half2_rn(cos2pi(u0), cos2pi(u1));
                S0 = __floats2half2_rn(sin2pi(u0), sin2pi(u1));
                float t2 = 2.f*av;       t2 -= floorf(t2);
                const float c2 = cos2pi(t2), s2 = sin2pi(t2);
                float t14 = 14.f*av;     t14 -= floorf(t14);
                const float c14 = cos2pi(t14), s14 = sin2pi(t14);
                c2h0  = __float2half2_rn(c2);   s2h0  = __float2half2_rn(s2);
                n2h0  = __float2half2_rn(-s2);
                c14h0 = __float2half2_rn(c14);  s14h0 = __float2half2_rn(s14);
                n14h0 = __float2half2_rn(-s14);
            }
            {   // row 1
                const float av = a.y;
                float u0 = hs*av;        u0 -= floorf(u0);
                float u1 = (hs+1.f)*av;  u1 -= floorf(u1);
                C1 = __floats2half2_rn(cos2pi(u0), cos2pi(u1));
                S1 = __floats2half2_rn(sin2pi(u0), sin2pi(u1));
                float t2 = 2.f*av;       t2 -= floorf(t2);
                const float c2 = cos2pi(t2), s2 = sin2pi(t2);
                float t14 = 14.f*av;     t14 -= floorf(t14);
                const float c14 = cos2pi(t14), s14 = sin2pi(t14);
                c2h1  = __float2half2_rn(c2);   s2h1  = __float2half2_rn(s2);
                n2h1  = __float2half2_rn(-s2);
                c14h1 = __float2half2_rn(c14);  s14h1 = __float2half2_rn(s14);
                n14h1 = __float2half2_rn(-s14);
            }
        }

        // fragment dwords straight from chain state (no conversions)
        u32x4 FCA, FCB, FSA, FSB;
        FCA.x = h2b(C0); FSA.x = h2b(S0); FCB.x = h2b(C1); FSB.x = h2b(S1);
        ADV(C0, S0, c2h0,  s2h0,  n2h0);  ADV(C1, S1, c2h1,  s2h1,  n2h1);
        FCA.y = h2b(C0); FSA.y = h2b(S0); FCB.y = h2b(C1); FSB.y = h2b(S1);
        ADV(C0, S0, c14h0, s14h0, n14h0); ADV(C1, S1, c14h1, s14h1, n14h1);
        FCA.z = h2b(C0); FSA.z = h2b(S0); FCB.z = h2b(C1); FSB.z = h2b(S1);
        ADV(C0, S0, c2h0,  s2h0,  n2h0);  ADV(C1, S1, c2h1,  s2h1,  n2h1);
        FCA.w = h2b(C0); FSA.w = h2b(S0); FCB.w = h2b(C1); FSB.w = h2b(S1);
        ADV(C0, S0, c14h0, s14h0, n14h0); ADV(C1, S1, c14h1, s14h1, n14h1);
        // state now at the next kk's anchor (h += 32)

        const half8 fAc = u4h(FCA);
        const half8 fBc = u4h(FCB);
        const half8 fAs = u4h(FSA);
        const half8 fBs = u4h(FSB);

        #pragma unroll
        for (int nt = 0; nt < 4; ++nt) {
            acc[0][nt] = __builtin_amdgcn_mfma_f32_16x16x32_f16(fAc, s8h(bfr[nt]),   acc[0][nt], 0, 0, 0);
            acc[1][nt] = __builtin_amdgcn_mfma_f32_16x16x32_f16(fBc, s8h(bfr[nt]),   acc[1][nt], 0, 0, 0);
            acc[0][nt] = __builtin_amdgcn_mfma_f32_16x16x32_f16(fAs, s8h(bfr[4+nt]), acc[0][nt], 0, 0, 0);
            acc[1][nt] = __builtin_amdgcn_mfma_f32_16x16x32_f16(fBs, s8h(bfr[4+nt]), acc[1][nt], 0, 0, 0);
        }
    }

    // Epilogue. D layout: col = lane&15, row = 4*(lane>>4) + reg  [m89-verified]
    #pragma unroll
    for (int rr = 0; rr < 2; ++rr) {
        const int row0 = base + rr*16 + kgrp*4;
        #pragma unroll
        for (int nt = 0; nt < 4; ++nt) {
            #pragma unroll
            for (int q = 0; q < 4; ++q) {
                out[(row0 + q)*ODIM + nt*16 + mrow] = acc[rr][nt][q] + bcol[nt];
            }
        }
    }
}

extern "C" void kernel_launch(void* const* d_in, const int* in_sizes, int n_in,
                              void* d_out, int out_size, void* d_ws, size_t ws_size,
                              hipStream_t stream) {
    const float* x      = (const float*)d_in[0];
    const float* coeffs = (const float*)d_in[1];
    const float* bias   = (const float*)d_in[2];
    float* out = (float*)d_out;
    short8* wfrag = (short8*)d_ws;    // 98304 B of workspace
    (void)in_sizes; (void)n_in; (void)out_size; (void)ws_size;
    hipLaunchKernelGGL(prep_weights, dim3((NFRAG + 255)/256), dim3(256), 0, stream, coeffs, wfrag);
    hipLaunchKernelGGL(fourier_main, dim3(NBLOCKS), dim3(TPB), 0, stream, x, wfrag, bias, out);
}

// Round 22
// 39.688 us; speedup vs baseline: 6.3225x; 6.3225x over previous
//
#include <hip/hip_runtime.h>
#include <hip/hip_fp16.h>

typedef __attribute__((ext_vector_type(8))) short short8;
typedef __attribute__((ext_vector_type(8))) _Float16 half8;
typedef __attribute__((ext_vector_type(4))) float f32x4;
typedef __attribute__((ext_vector_type(2))) float f32x2;
typedef __attribute__((ext_vector_type(4))) unsigned int u32x4;

#define NROWS   262144
#define ODIM    64
#define NBLOCKS 256
#define TPB     1024          // 16 waves; 98 KB LDS -> 1 block/CU -> 4 waves/SIMD
#define INV2PI  0.15915494309189535f

__device__ __forceinline__ float cos2pi(float f){ float r; asm("v_cos_f32 %0, %1" : "=v"(r) : "v"(f)); return r; }
__device__ __forceinline__ float sin2pi(float f){ float r; asm("v_sin_f32 %0, %1" : "=v"(r) : "v"(f)); return r; }

__device__ __forceinline__ short f16_of(float f){
    union { _Float16 h; short s; } u; u.h = (_Float16)f; return u.s; }
__device__ __forceinline__ unsigned h2b(__half2 h){
    union { __half2 h; unsigned u; } x; x.h = h; return x.u; }
__device__ __forceinline__ half8 u4h(u32x4 v){ union{u32x4 u; half8 h;} x; x.u = v; return x.h; }
__device__ __forceinline__ half8 s8h(short8 v){ union{short8 s; half8 h;} x; x.s = v; return x.h; }

// rotate a packed (cos,sin) dword pair by const rotation (RC,RS,RN=-RS):
//   Cd = C*RC - S*RS ; Sd = S*RC + C*RS      (2 features per instruction)
#define ROT(CD, SD, C, S, RC, RS, RN) do {               \
    CD = __hfma2(C, RC, __hmul2(S, RN));                 \
    SD = __hfma2(S, RC, __hmul2(C, RS));                 \
} while (0)

// out[b,o] = sum_k F[b,k] W[o,k]; k = br*384 + i*128 + g; harmonic = g+1
// cos k-step kk (0..11) pairs with sin k-step kk+12 (identical harmonics).
// R22 = R17 with the FEAT walk restructured for minimal critical path:
//   dword x = anchor; y = x(+2); z = x(+16) [parallel with y]; w = y(+16);
//   next anchor = x(+32) computed FIRST (depth-1 chain across kk, vs 4 serial ADVs).
extern "C" __global__ void __launch_bounds__(TPB, 4)
__attribute__((amdgpu_waves_per_eu(4, 4)))
fourier_mfma(const float* __restrict__ x,
             const float* __restrict__ coeffs,
             const float* __restrict__ bias,
             float* __restrict__ out)
{
    // Fragment-ordered f16 weights: [ks][nt][lane] -> 8 f16 (one ds_read_b128)
    __shared__ short8 Wlds[24 * 4 * 64];   // 98304 B

    const int tid = threadIdx.x;

    // ---- one-time weight staging: fp32 global -> f16 fragments in LDS ----
    for (int fl = tid; fl < 24*4*64; fl += TPB) {
        const int ks = fl >> 8;
        const int nt = (fl >> 6) & 3;
        const int ln = fl & 63;
        const int o  = nt*16 + (ln & 15);   // B-frag: col = lane & 15
        const int kg = ln >> 4;             // k sub-band = 4*(lane>>4)
        union { short8 v; short s[8]; } fr;
        #pragma unroll
        for (int h = 0; h < 2; ++h) {
            const int kb  = ks*32 + h*16;
            const int br  = (kb >= 384) ? 1 : 0;
            const int rem = kb - br*384;
            const int ii  = rem >> 7;
            const int g0  = (rem & 127) + kg*4;
            const float* wp = coeffs + (((br*ODIM + o)*3 + ii) << 7) + g0;
            #pragma unroll
            for (int j = 0; j < 4; ++j) fr.s[h*4 + j] = f16_of(wp[j]);
        }
        Wlds[fl] = fr.v;
    }
    __syncthreads();

    const int lane = tid & 63;
    const int wid  = tid >> 6;
    const int mrow = lane & 15;     // A-frag row within 16-row tile
    const int kgrp = lane >> 4;     // k sub-band / D-row group
    const float hs = (float)(4*kgrp + 1);   // lane's anchor harmonic per i-block

    float bcol[4];
    #pragma unroll
    for (int nt = 0; nt < 4; ++nt) bcol[nt] = bias[nt*16 + mrow];

    const int unit = blockIdx.x * 16 + wid;   // 256*16 = 4096 units = NROWS/64
    const int base = unit * 64;

    // Two sequential 32-row passes; each pass handles a row-pair (rows r0, r1).
    #pragma unroll 1
    for (int rg = 0; rg < 2; ++rg) {
        const int rowA = base + (rg*2 + 0)*16 + mrow;
        const int rowB = base + (rg*2 + 1)*16 + mrow;

        f32x2 xr[3];
        #pragma unroll
        for (int i = 0; i < 3; ++i)
            xr[i] = (f32x2){ x[rowA*3 + i] * INV2PI, x[rowB*3 + i] * INV2PI };

        f32x4 acc[2][4];
        #pragma unroll
        for (int rr = 0; rr < 2; ++rr)
            #pragma unroll
            for (int nt = 0; nt < 4; ++nt)
                acc[rr][nt] = (f32x4){0.f, 0.f, 0.f, 0.f};

        // anchor state + rotation constants (per row): +2, +16, +32
        __half2 C0, S0, C1, S1;
        __half2 c2h0, s2h0, n2h0, c16h0, s16h0, n16h0, c32h0, s32h0, n32h0;
        __half2 c2h1, s2h1, n2h1, c16h1, s16h1, n16h1, c32h1, s32h1, n32h1;

        #pragma unroll 1
        for (int kk = 0; kk < 12; ++kk) {          // cos k-step; sin is kk+12
            // early-issue this step's 8 b-frags (latency hides under feature gen)
            short8 bfr[8];                          // [branch*4 + nt], static idx
            #pragma unroll
            for (int nt = 0; nt < 4; ++nt) {
                bfr[nt]     = Wlds[(kk*4 + nt)*64 + lane];
                bfr[4 + nt] = Wlds[((kk + 12)*4 + nt)*64 + lane];
            }

            if ((kk & 3) == 0) {                    // re-anchor per i-block (uniform)
                const int i = kk >> 2;
                const f32x2 a = xr[i];
                {   // row 0
                    const float av = a.x;
                    float u0 = hs*av;        u0 -= floorf(u0);
                    float u1 = (hs+1.f)*av;  u1 -= floorf(u1);
                    C0 = __floats2half2_rn(cos2pi(u0), cos2pi(u1));
                    S0 = __floats2half2_rn(sin2pi(u0), sin2pi(u1));
                    float t2 = 2.f*av;       t2 -= floorf(t2);
                    const float c2 = cos2pi(t2), s2 = sin2pi(t2);
                    float t16 = 16.f*av;     t16 -= floorf(t16);
                    const float c16 = cos2pi(t16), s16 = sin2pi(t16);
                    float t32 = 32.f*av;     t32 -= floorf(t32);
                    const float c32 = cos2pi(t32), s32 = sin2pi(t32);
                    c2h0  = __float2half2_rn(c2);   s2h0  = __float2half2_rn(s2);
                    n2h0  = __float2half2_rn(-s2);
                    c16h0 = __float2half2_rn(c16);  s16h0 = __float2half2_rn(s16);
                    n16h0 = __float2half2_rn(-s16);
                    c32h0 = __float2half2_rn(c32);  s32h0 = __float2half2_rn(s32);
                    n32h0 = __float2half2_rn(-s32);
                }
                {   // row 1
                    const float av = a.y;
                    float u0 = hs*av;        u0 -= floorf(u0);
                    float u1 = (hs+1.f)*av;  u1 -= floorf(u1);
                    C1 = __floats2half2_rn(cos2pi(u0), cos2pi(u1));
                    S1 = __floats2half2_rn(sin2pi(u0), sin2pi(u1));
                    float t2 = 2.f*av;       t2 -= floorf(t2);
                    const float c2 = cos2pi(t2), s2 = sin2pi(t2);
                    float t16 = 16.f*av;     t16 -= floorf(t16);
                    const float c16 = cos2pi(t16), s16 = sin2pi(t16);
                    float t32 = 32.f*av;     t32 -= floorf(t32);
                    const float c32 = cos2pi(t32), s32 = sin2pi(t32);
                    c2h1  = __float2half2_rn(c2);   s2h1  = __float2half2_rn(s2);
                    n2h1  = __float2half2_rn(-s2);
                    c16h1 = __float2half2_rn(c16);  s16h1 = __float2half2_rn(s16);
                    n16h1 = __float2half2_rn(-s16);
                    c32h1 = __float2half2_rn(c32);  s32h1 = __float2half2_rn(s32);
                    n32h1 = __float2half2_rn(-s32);
                }
            }

            // FEAT: x = anchor; advance anchor first (depth-1 inter-kk chain);
            // y = x+2, z = x+16 (parallel), w = y+16 (depth 2).
            u32x4 FCA, FCB, FSA, FSB;
            {
                const __half2 Cx0 = C0, Sx0 = S0, Cx1 = C1, Sx1 = S1;
                FCA.x = h2b(Cx0); FSA.x = h2b(Sx0);
                FCB.x = h2b(Cx1); FSB.x = h2b(Sx1);
                // next anchor (earliest possible, off old state)
                ROT(C0, S0, Cx0, Sx0, c32h0, s32h0, n32h0);
                ROT(C1, S1, Cx1, Sx1, c32h1, s32h1, n32h1);
                // y = x + 2
                __half2 Cy0, Sy0, Cy1, Sy1;
                ROT(Cy0, Sy0, Cx0, Sx0, c2h0, s2h0, n2h0);
                ROT(Cy1, Sy1, Cx1, Sx1, c2h1, s2h1, n2h1);
                FCA.y = h2b(Cy0); FSA.y = h2b(Sy0);
                FCB.y = h2b(Cy1); FSB.y = h2b(Sy1);
                // z = x + 16 (independent of y)
                __half2 Cz0, Sz0, Cz1, Sz1;
                ROT(Cz0, Sz0, Cx0, Sx0, c16h0, s16h0, n16h0);
                ROT(Cz1, Sz1, Cx1, Sx1, c16h1, s16h1, n16h1);
                FCA.z = h2b(Cz0); FSA.z = h2b(Sz0);
                FCB.z = h2b(Cz1); FSB.z = h2b(Sz1);
                // w = y + 16
                __half2 Cw0, Sw0, Cw1, Sw1;
                ROT(Cw0, Sw0, Cy0, Sy0, c16h0, s16h0, n16h0);
                ROT(Cw1, Sw1, Cy1, Sy1, c16h1, s16h1, n16h1);
                FCA.w = h2b(Cw0); FSA.w = h2b(Sw0);
                FCB.w = h2b(Cw1); FSB.w = h2b(Sw1);
            }

            const half8 fAc = u4h(FCA);
            const half8 fBc = u4h(FCB);
            const half8 fAs = u4h(FSA);
            const half8 fBs = u4h(FSB);

            #pragma unroll
            for (int nt = 0; nt < 4; ++nt) {
                acc[0][nt] = __builtin_amdgcn_mfma_f32_16x16x32_f16(fAc, s8h(bfr[nt]),   acc[0][nt], 0, 0, 0);
                acc[1][nt] = __builtin_amdgcn_mfma_f32_16x16x32_f16(fBc, s8h(bfr[nt]),   acc[1][nt], 0, 0, 0);
                acc[0][nt] = __builtin_amdgcn_mfma_f32_16x16x32_f16(fAs, s8h(bfr[4+nt]), acc[0][nt], 0, 0, 0);
                acc[1][nt] = __builtin_amdgcn_mfma_f32_16x16x32_f16(fBs, s8h(bfr[4+nt]), acc[1][nt], 0, 0, 0);
            }
        }

        // Epilogue. D layout: col = lane&15, row = 4*(lane>>4) + reg  [m89-verified]
        #pragma unroll
        for (int rr = 0; rr < 2; ++rr) {
            const int row0 = base + (rg*2 + rr)*16 + kgrp*4;
            #pragma unroll
            for (int nt = 0; nt < 4; ++nt) {
                #pragma unroll
                for (int q = 0; q < 4; ++q) {
                    out[(row0 + q)*ODIM + nt*16 + mrow] = acc[rr][nt][q] + bcol[nt];
                }
            }
        }
    }
}

extern "C" void kernel_launch(void* const* d_in, const int* in_sizes, int n_in,
                              void* d_out, int out_size, void* d_ws, size_t ws_size,
                              hipStream_t stream) {
    const float* x      = (const float*)d_in[0];
    const float* coeffs = (const float*)d_in[1];
    const float* bias   = (const float*)d_in[2];
    float* out = (float*)d_out;
    (void)in_sizes; (void)n_in; (void)out_size; (void)d_ws; (void)ws_size;
    hipLaunchKernelGGL(fourier_mfma, dim3(NBLOCKS), dim3(TPB), 0, stream, x, coeffs, bias, out);
}

// Round 23
// 38.743 us; speedup vs baseline: 6.4768x; 1.0244x over previous
//
#include <hip/hip_runtime.h>
#include <hip/hip_fp16.h>

typedef __attribute__((ext_vector_type(8))) short short8;
typedef __attribute__((ext_vector_type(8))) _Float16 half8;
typedef __attribute__((ext_vector_type(4))) float f32x4;
typedef __attribute__((ext_vector_type(2))) float f32x2;
typedef __attribute__((ext_vector_type(4))) unsigned int u32x4;

#define NROWS   262144
#define ODIM    64
#define NBLOCKS 256
#define TPB     1024          // 16 waves; 98 KB LDS -> 1 block/CU -> 4 waves/SIMD
#define INV2PI  0.15915494309189535f

__device__ __forceinline__ float cos2pi(float f){ float r; asm("v_cos_f32 %0, %1" : "=v"(r) : "v"(f)); return r; }
__device__ __forceinline__ float sin2pi(float f){ float r; asm("v_sin_f32 %0, %1" : "=v"(r) : "v"(f)); return r; }

__device__ __forceinline__ short f16_of(float f){
    union { _Float16 h; short s; } u; u.h = (_Float16)f; return u.s; }
__device__ __forceinline__ unsigned h2b(__half2 h){
    union { __half2 h; unsigned u; } x; x.h = h; return x.u; }
__device__ __forceinline__ half8 u4h(u32x4 v){ union{u32x4 u; half8 h;} x; x.u = v; return x.h; }
__device__ __forceinline__ half8 s8h(short8 v){ union{short8 s; half8 h;} x; x.s = v; return x.h; }

// one packed rotation: (C,S) <- (C*rc - S*rs, S*rc + C*rs), 2 features/inst
#define ADV(C, S, RC, RS, RN) do {                       \
    const __half2 _cn = __hfma2(C, RC, __hmul2(S, RN));  \
    const __half2 _sn = __hfma2(S, RC, __hmul2(C, RS));  \
    C = _cn; S = _sn;                                    \
} while (0)

// out[b,o] = sum_k F[b,k] W[o,k]; k = br*384 + i*128 + g; harmonic = g+1
// cos k-step kk (0..11) pairs with sin k-step kk+12 (identical harmonics).
// Frag element s[h*4+j] <-> harmonic (kk&3)*32 + h*16 + kgrp*4 + j + 1 within i-block.
// Dword view: pairs at harmonic offsets {0,2,16,18} -> advances +2,+14,+2,+14 (chain
// carries across kk inside an i-block; re-anchored every 4 kk).
extern "C" __global__ void __launch_bounds__(TPB, 4)
__attribute__((amdgpu_waves_per_eu(4, 4)))
fourier_mfma(const float* __restrict__ x,
             const float* __restrict__ coeffs,
             const float* __restrict__ bias,
             float* __restrict__ out)
{
    // Fragment-ordered f16 weights: [ks][nt][lane] -> 8 f16 (one ds_read_b128)
    __shared__ short8 Wlds[24 * 4 * 64];   // 98304 B

    const int tid = threadIdx.x;

    // ---- one-time weight staging: fp32 global -> f16 fragments in LDS ----
    for (int fl = tid; fl < 24*4*64; fl += TPB) {
        const int ks = fl >> 8;
        const int nt = (fl >> 6) & 3;
        const int ln = fl & 63;
        const int o  = nt*16 + (ln & 15);   // B-frag: col = lane & 15
        const int kg = ln >> 4;             // k sub-band = 4*(lane>>4)
        union { short8 v; short s[8]; } fr;
        #pragma unroll
        for (int h = 0; h < 2; ++h) {
            const int kb  = ks*32 + h*16;
            const int br  = (kb >= 384) ? 1 : 0;
            const int rem = kb - br*384;
            const int ii  = rem >> 7;
            const int g0  = (rem & 127) + kg*4;
            const float* wp = coeffs + (((br*ODIM + o)*3 + ii) << 7) + g0;
            #pragma unroll
            for (int j = 0; j < 4; ++j) fr.s[h*4 + j] = f16_of(wp[j]);
        }
        Wlds[fl] = fr.v;
    }
    __syncthreads();

    const int lane = tid & 63;
    const int wid  = tid >> 6;
    const int mrow = lane & 15;     // A-frag row within 16-row tile
    const int kgrp = lane >> 4;     // k sub-band / D-row group
    const float hs = (float)(4*kgrp + 1);   // lane's anchor harmonic per i-block

    float bcol[4];
    #pragma unroll
    for (int nt = 0; nt < 4; ++nt) bcol[nt] = bias[nt*16 + mrow];

    const int unit = blockIdx.x * 16 + wid;   // 256*16 = 4096 units = NROWS/64
    const int base = unit * 64;

    // Two sequential 32-row passes; each pass handles a row-pair (rows r0, r1).
    #pragma unroll 1
    for (int rg = 0; rg < 2; ++rg) {
        const int rowA = base + (rg*2 + 0)*16 + mrow;
        const int rowB = base + (rg*2 + 1)*16 + mrow;

        f32x2 xr[3];
        #pragma unroll
        for (int i = 0; i < 3; ++i)
            xr[i] = (f32x2){ x[rowA*3 + i] * INV2PI, x[rowB*3 + i] * INV2PI };

        f32x4 acc[2][4];
        #pragma unroll
        for (int rr = 0; rr < 2; ++rr)
            #pragma unroll
            for (int nt = 0; nt < 4; ++nt)
                acc[rr][nt] = (f32x4){0.f, 0.f, 0.f, 0.f};

        // chain state + rotation constants (per row)
        __half2 C0, S0, C1, S1;
        __half2 c2h0, s2h0, n2h0, c14h0, s14h0, n14h0;
        __half2 c2h1, s2h1, n2h1, c14h1, s14h1, n14h1;

        #pragma unroll 1
        for (int kk = 0; kk < 12; ++kk) {          // cos k-step; sin is kk+12
            // early-issue this step's 8 b-frags (latency hides under feature gen)
            short8 bfr[8];                          // [branch*4 + nt], static idx
            #pragma unroll
            for (int nt = 0; nt < 4; ++nt) {
                bfr[nt]     = Wlds[(kk*4 + nt)*64 + lane];
                bfr[4 + nt] = Wlds[((kk + 12)*4 + nt)*64 + lane];
            }

            if ((kk & 3) == 0) {                    // re-anchor per i-block (uniform)
                const int i = kk >> 2;
                const f32x2 a = xr[i];
                {   // row 0
                    const float av = a.x;
                    float u0 = hs*av;        u0 -= floorf(u0);
                    float u1 = (hs+1.f)*av;  u1 -= floorf(u1);
                    C0 = __floats2half2_rn(cos2pi(u0), cos2pi(u1));
                    S0 = __floats2half2_rn(sin2pi(u0), sin2pi(u1));
                    float t2 = 2.f*av;       t2 -= floorf(t2);
                    const float c2 = cos2pi(t2), s2 = sin2pi(t2);
                    float t14 = 14.f*av;     t14 -= floorf(t14);
                    const float c14 = cos2pi(t14), s14 = sin2pi(t14);
                    c2h0  = __float2half2_rn(c2);   s2h0  = __float2half2_rn(s2);
                    n2h0  = __float2half2_rn(-s2);
                    c14h0 = __float2half2_rn(c14);  s14h0 = __float2half2_rn(s14);
                    n14h0 = __float2half2_rn(-s14);
                }
                {   // row 1
                    const float av = a.y;
                    float u0 = hs*av;        u0 -= floorf(u0);
                    float u1 = (hs+1.f)*av;  u1 -= floorf(u1);
                    C1 = __floats2half2_rn(cos2pi(u0), cos2pi(u1));
                    S1 = __floats2half2_rn(sin2pi(u0), sin2pi(u1));
                    float t2 = 2.f*av;       t2 -= floorf(t2);
                    const float c2 = cos2pi(t2), s2 = sin2pi(t2);
                    float t14 = 14.f*av;     t14 -= floorf(t14);
                    const float c14 = cos2pi(t14), s14 = sin2pi(t14);
                    c2h1  = __float2half2_rn(c2);   s2h1  = __float2half2_rn(s2);
                    n2h1  = __float2half2_rn(-s2);
                    c14h1 = __float2half2_rn(c14);  s14h1 = __float2half2_rn(s14);
                    n14h1 = __float2half2_rn(-s14);
                }
            }

            // fragment dwords straight from chain state (no conversions)
            u32x4 FCA, FCB, FSA, FSB;
            FCA.x = h2b(C0); FSA.x = h2b(S0); FCB.x = h2b(C1); FSB.x = h2b(S1);
            ADV(C0, S0, c2h0,  s2h0,  n2h0);  ADV(C1, S1, c2h1,  s2h1,  n2h1);
            FCA.y = h2b(C0); FSA.y = h2b(S0); FCB.y = h2b(C1); FSB.y = h2b(S1);
            ADV(C0, S0, c14h0, s14h0, n14h0); ADV(C1, S1, c14h1, s14h1, n14h1);
            FCA.z = h2b(C0); FSA.z = h2b(S0); FCB.z = h2b(C1); FSB.z = h2b(S1);
            ADV(C0, S0, c2h0,  s2h0,  n2h0);  ADV(C1, S1, c2h1,  s2h1,  n2h1);
            FCA.w = h2b(C0); FSA.w = h2b(S0); FCB.w = h2b(C1); FSB.w = h2b(S1);
            ADV(C0, S0, c14h0, s14h0, n14h0); ADV(C1, S1, c14h1, s14h1, n14h1);
            // state now at harmonic anchor+32 = next kk's anchor

            const half8 fAc = u4h(FCA);
            const half8 fBc = u4h(FCB);
            const half8 fAs = u4h(FSA);
            const half8 fBs = u4h(FSB);

            #pragma unroll
            for (int nt = 0; nt < 4; ++nt) {
                acc[0][nt] = __builtin_amdgcn_mfma_f32_16x16x32_f16(fAc, s8h(bfr[nt]),   acc[0][nt], 0, 0, 0);
                acc[1][nt] = __builtin_amdgcn_mfma_f32_16x16x32_f16(fBc, s8h(bfr[nt]),   acc[1][nt], 0, 0, 0);
                acc[0][nt] = __builtin_amdgcn_mfma_f32_16x16x32_f16(fAs, s8h(bfr[4+nt]), acc[0][nt], 0, 0, 0);
                acc[1][nt] = __builtin_amdgcn_mfma_f32_16x16x32_f16(fBs, s8h(bfr[4+nt]), acc[1][nt], 0, 0, 0);
            }
        }

        // Epilogue. D layout: col = lane&15, row = 4*(lane>>4) + reg  [m89-verified]
        #pragma unroll
        for (int rr = 0; rr < 2; ++rr) {
            const int row0 = base + (rg*2 + rr)*16 + kgrp*4;
            #pragma unroll
            for (int nt = 0; nt < 4; ++nt) {
                #pragma unroll
                for (int q = 0; q < 4; ++q) {
                    out[(row0 + q)*ODIM + nt*16 + mrow] = acc[rr][nt][q] + bcol[nt];
                }
            }
        }
    }
}

extern "C" void kernel_launch(void* const* d_in, const int* in_sizes, int n_in,
                              void* d_out, int out_size, void* d_ws, size_t ws_size,
                              hipStream_t stream) {
    const float* x      = (const float*)d_in[0];
    const float* coeffs = (const float*)d_in[1];
    const float* bias   = (const float*)d_in[2];
    float* out = (float*)d_out;
    (void)in_sizes; (void)n_in; (void)out_size; (void)d_ws; (void)ws_size;
    hipLaunchKernelGGL(fourier_mfma, dim3(NBLOCKS), dim3(TPB), 0, stream, x, coeffs, bias, out);
}